// Round 1
// 1063.888 us; speedup vs baseline: 1.1900x; 1.1900x over previous
//
#include <hip/hip_runtime.h>

// PathCon FFN — round 2: kill per-MFMA global weight fetches.
// ffn v2: persistent blocks (grid=256, 1024 thr = 16 waves), each wave owns a
// 16-col N-slice of all three GEMMs; weight fragments live in 80 VGPRs loaded
// once per block. 64 edges/block-iter staged via LDS; LN via DPP row_ror
// reduction + cross-wave LDS tree. Weight L2 traffic: 4.1 GB -> ~80 MB.

constexpr int NN = 50000;
constexpr int NE = 400000;
constexpr int DI = 128;
constexpr int DN = 6;
constexpr int DR = 134;
constexpr float LN_EPS = 1e-5f;

using f4 = __attribute__((ext_vector_type(4))) float;
using s8 = __attribute__((ext_vector_type(8))) short;

__device__ __forceinline__ unsigned short f2bf(float f) {
    unsigned u = __float_as_uint(f);
    u += 0x7fff + ((u >> 16) & 1);   // RNE
    return (unsigned short)(u >> 16);
}

__device__ __forceinline__ float bf2f(unsigned short b) {
    return __uint_as_float((unsigned)b << 16);
}

// Sum across each aligned 16-lane group via DPP row rotations (VALU pipe, no LDS).
// After 4 steps every lane holds the 16-lane group sum.
__device__ __forceinline__ float red16(float v) {
    int x;
    x = __builtin_amdgcn_update_dpp(0, __float_as_int(v), 0x121, 0xf, 0xf, true); // row_ror:1
    v += __int_as_float(x);
    x = __builtin_amdgcn_update_dpp(0, __float_as_int(v), 0x122, 0xf, 0xf, true); // row_ror:2
    v += __int_as_float(x);
    x = __builtin_amdgcn_update_dpp(0, __float_as_int(v), 0x124, 0xf, 0xf, true); // row_ror:4
    v += __int_as_float(x);
    x = __builtin_amdgcn_update_dpp(0, __float_as_int(v), 0x128, 0xf, 0xf, true); // row_ror:8
    v += __int_as_float(x);
    return v;
}

// ---------------------------------------------------------------- scatter ---
__global__ __launch_bounds__(256) void scatter_kernel(
    const float* __restrict__ edge_attr, const float* __restrict__ mask,
    const int* __restrict__ ei, float* __restrict__ node_out,
    float* __restrict__ den)
{
    int i = blockIdx.x * 256 + threadIdx.x;
    if (i >= NE * 32) return;
    int e = i >> 5, q = i & 31;
    float m = mask[e];
    if (m == 0.f) return;
    int col = ei[NE + e];
    if (q == 0) atomicAdd(&den[col], m);
    float4 v = reinterpret_cast<const float4*>(edge_attr)[(size_t)e * 32 + q];
    float* dst = node_out + (size_t)col * DR + q * 4;
    atomicAdd(dst + 0, v.x * m);
    atomicAdd(dst + 1, v.y * m);
    atomicAdd(dst + 2, v.z * m);
    atomicAdd(dst + 3, v.w * m);
}

// --------------------------------------------------------------- finalize ---
__global__ __launch_bounds__(256) void finalize_node_kernel(
    const float* __restrict__ x, const float* __restrict__ den,
    float* __restrict__ node_out)
{
    int i = blockIdx.x * 256 + threadIdx.x;
    if (i >= NN * DR) return;
    int n = i / DR;
    int d = i - n * DR;
    if (d < DI) node_out[i] = node_out[i] / (den[n] + 1.0f);
    else        node_out[i] = x[n * DN + (d - DI)];
}

// ----------------------------------------------------- bf16 weight prep ---
// WcT'[n][k] = W_edge[268+k][n] + (k==n)   (128x128)
// W1T [n][k] = W1[k][n]                    (256x128)
// W2T [n][k] = W2[k][n]                    (128x256)
__global__ __launch_bounds__(256) void prep_w_kernel(
    const float* __restrict__ W_edge, const float* __restrict__ W1,
    const float* __restrict__ W2,
    unsigned short* __restrict__ WcT, unsigned short* __restrict__ W1T,
    unsigned short* __restrict__ W2T)
{
    int idx = blockIdx.x * 256 + threadIdx.x;
    if (idx < 16384) {
        int n = idx >> 7, k = idx & 127;
        float v = W_edge[(268 + k) * 128 + n] + (k == n ? 1.f : 0.f);
        WcT[n * 128 + k] = f2bf(v);
    } else if (idx < 49152) {
        int j = idx - 16384;
        int n = j >> 7, k = j & 127;
        W1T[n * 128 + k] = f2bf(W1[k * 256 + n]);
    } else if (idx < 81920) {
        int j = idx - 49152;
        int n = j >> 8, k = j & 255;
        W2T[n * 256 + k] = f2bf(W2[k * 128 + n]);
    }
}

// ------------------------------------------------ P/Q node-level GEMMs ---
// P = node_rep @ Wa + b_edge ; Q = node_rep @ Wb   (K=134 padded to 136)
__global__ __launch_bounds__(256) void pq_kernel(
    const float* __restrict__ nr, const float* __restrict__ W_edge,
    const float* __restrict__ b_edge,
    float* __restrict__ P, float* __restrict__ Q)
{
    __shared__ float As[32 * 136];
    const int t = threadIdx.x;
    const int n0 = blockIdx.x * 32;

    for (int idx = t; idx < 32 * 136; idx += 256) {
        int n = idx / 136, k = idx - n * 136;
        float v = 0.f;
        if (n0 + n < NN && k < DR) v = nr[(size_t)(n0 + n) * DR + k];
        As[idx] = v;
    }
    __syncthreads();

    const int et = t >> 5, jt = t & 31;
    float4 accP[4], accQ[4];
    #pragma unroll
    for (int i = 0; i < 4; ++i) {
        accP[i] = make_float4(0.f, 0.f, 0.f, 0.f);
        accQ[i] = make_float4(0.f, 0.f, 0.f, 0.f);
    }
    for (int k0 = 0; k0 < 136; k0 += 4) {
        float4 wa[4], wb[4];
        #pragma unroll
        for (int d = 0; d < 4; ++d) {
            wa[d] = *reinterpret_cast<const float4*>(&W_edge[(size_t)(k0 + d) * 128 + 4 * jt]);
            wb[d] = *reinterpret_cast<const float4*>(&W_edge[(size_t)(134 + k0 + d) * 128 + 4 * jt]);
        }
        #pragma unroll
        for (int i = 0; i < 4; ++i) {
            float4 a4 = *reinterpret_cast<const float4*>(&As[(4 * et + i) * 136 + k0]);
            accP[i].x += a4.x * wa[0].x + a4.y * wa[1].x + a4.z * wa[2].x + a4.w * wa[3].x;
            accP[i].y += a4.x * wa[0].y + a4.y * wa[1].y + a4.z * wa[2].y + a4.w * wa[3].y;
            accP[i].z += a4.x * wa[0].z + a4.y * wa[1].z + a4.z * wa[2].z + a4.w * wa[3].z;
            accP[i].w += a4.x * wa[0].w + a4.y * wa[1].w + a4.z * wa[2].w + a4.w * wa[3].w;
            accQ[i].x += a4.x * wb[0].x + a4.y * wb[1].x + a4.z * wb[2].x + a4.w * wb[3].x;
            accQ[i].y += a4.x * wb[0].y + a4.y * wb[1].y + a4.z * wb[2].y + a4.w * wb[3].y;
            accQ[i].z += a4.x * wb[0].z + a4.y * wb[1].z + a4.z * wb[2].z + a4.w * wb[3].z;
            accQ[i].w += a4.x * wb[0].w + a4.y * wb[1].w + a4.z * wb[2].w + a4.w * wb[3].w;
        }
    }
    float4 bev = *reinterpret_cast<const float4*>(&b_edge[4 * jt]);
    #pragma unroll
    for (int i = 0; i < 4; ++i) {
        int n = n0 + 4 * et + i;
        if (n < NN) {
            float4 p = accP[i];
            p.x += bev.x; p.y += bev.y; p.z += bev.z; p.w += bev.w;
            *reinterpret_cast<float4*>(&P[(size_t)n * 128 + 4 * jt]) = p;
            *reinterpret_cast<float4*>(&Q[(size_t)n * 128 + 4 * jt]) = accQ[i];
        }
    }
}

// -------------------------------------------------------------- fused FFN ---
// Block: 1024 threads = 16 waves = 2 m-groups (32 edges each) x 8 col-waves.
// Wave (mg, cw): computes cols [cw*16, cw*16+16) of GEMM1/GEMM3 and
// cols [cw*32, cw*32+32) of GEMM2, for its m-group's 32 edges.
// Weights: held in VGPRs for the whole kernel (loaded once per block).
constexpr int PA = 136;          // pitch (shorts) of ea/h tile rows
constexpr int PU = 264;          // pitch (shorts) of u tile rows
constexpr int ET = 64;           // edges per block-iteration
constexpr int NTILE = NE / ET;   // 6250

__global__ __launch_bounds__(1024, 4) void ffn_kernel(
    const float* __restrict__ edge_attr,  // [NE, 128]
    const int* __restrict__ ei,           // [2, NE]
    const float* __restrict__ P,          // [NN, 128]
    const float* __restrict__ Q,          // [NN, 128]
    const unsigned short* __restrict__ WcT,   // [128][128] bf16 (Wc+I)^T
    const unsigned short* __restrict__ W1T,   // [256][128] bf16
    const unsigned short* __restrict__ W2T,   // [128][256] bf16
    const float* __restrict__ b1, const float* __restrict__ b2,
    const float* __restrict__ g1, const float* __restrict__ be1,
    const float* __restrict__ g2, const float* __restrict__ be2,
    float* __restrict__ out)              // [NE, 128]
{
    __shared__ short lds_a[ET * PA];          // ea tile, later h tile (17408 B)
    __shared__ short lds_u[ET * PU];          // u tile (33792 B)
    __shared__ float red_part[2][8][32][2];   // [mg][cw][row][s,ss] (4096 B)
    __shared__ float musig[2][ET][2];         // [ln][row][mu,rs]    (1024 B)

    const int t    = threadIdx.x;
    const int w    = t >> 6;
    const int lane = t & 63;
    const int q    = lane >> 4;     // 0..3
    const int c    = lane & 15;     // 0..15
    const int mg   = w >> 3;        // 0..1   (m-group: which 32 edges)
    const int cw   = w & 7;         // 0..7   (col-slice)

    // ---- persistent weight fragments (loaded once per block) ----
    s8 wcf[4], w1f[2][4], w2f[8];                 // 80 VGPRs
    #pragma unroll
    for (int k0 = 0; k0 < 4; ++k0)
        wcf[k0] = *reinterpret_cast<const s8*>(WcT + (cw * 16 + c) * 128 + k0 * 32 + q * 8);
    #pragma unroll
    for (int nt = 0; nt < 2; ++nt)
        #pragma unroll
        for (int k0 = 0; k0 < 4; ++k0)
            w1f[nt][k0] = *reinterpret_cast<const s8*>(W1T + (cw * 32 + nt * 16 + c) * 128 + k0 * 32 + q * 8);
    #pragma unroll
    for (int k0 = 0; k0 < 8; ++k0)
        w2f[k0] = *reinterpret_cast<const s8*>(W2T + (cw * 16 + c) * 256 + k0 * 32 + q * 8);

    const float g1c  = g1[cw * 16 + c],  be1c = be1[cw * 16 + c];
    const float b1v0 = b1[cw * 32 + c],  b1v1 = b1[cw * 32 + 16 + c];
    const float b2c  = b2[cw * 16 + c];
    const float g2c  = g2[cw * 16 + c],  be2c = be2[cw * 16 + c];

    const int srow = t >> 4;    // staging: 0..63
    const int sti  = t & 15;    // staging: 16 threads per row

    for (int tile = blockIdx.x; tile < NTILE; tile += gridDim.x) {
        const int e0 = tile * ET;

        // ---- stage ea tile -> bf16 LDS (all 1024 threads, 8 floats each) ----
        {
            const float4* src = reinterpret_cast<const float4*>(
                edge_attr + (size_t)(e0 + srow) * 128 + sti * 8);
            float4 v0 = src[0], v1 = src[1];
            s8 bb;
            bb[0] = (short)f2bf(v0.x); bb[1] = (short)f2bf(v0.y);
            bb[2] = (short)f2bf(v0.z); bb[3] = (short)f2bf(v0.w);
            bb[4] = (short)f2bf(v1.x); bb[5] = (short)f2bf(v1.y);
            bb[6] = (short)f2bf(v1.z); bb[7] = (short)f2bf(v1.w);
            *reinterpret_cast<s8*>(&lds_a[srow * PA + sti * 8]) = bb;
        }
        __syncthreads();                                   // (A) ea ready

        // ---- GEMM1: ea @ (Wc+I), this wave's 16 cols x 32 edges ----
        f4 acc1[2];
        acc1[0] = {0.f, 0.f, 0.f, 0.f};
        acc1[1] = {0.f, 0.f, 0.f, 0.f};
        #pragma unroll
        for (int k0 = 0; k0 < 4; ++k0)
            #pragma unroll
            for (int mt = 0; mt < 2; ++mt) {
                s8 a = *reinterpret_cast<const s8*>(&lds_a[(mg * 32 + mt * 16 + c) * PA + k0 * 32 + q * 8]);
                acc1[mt] = __builtin_amdgcn_mfma_f32_16x16x32_bf16(a, wcf[k0], acc1[mt], 0, 0, 0);
            }

        // ---- residual: + P[row_e] + Q[col_e] (only this wave's 16 cols) ----
        #pragma unroll
        for (int mt = 0; mt < 2; ++mt)
            #pragma unroll
            for (int reg = 0; reg < 4; ++reg) {
                int e  = e0 + mg * 32 + mt * 16 + q * 4 + reg;
                int er = ei[e], ec = ei[NE + e];
                acc1[mt][reg] += P[(size_t)er * 128 + cw * 16 + c]
                               + Q[(size_t)ec * 128 + cw * 16 + c];
            }

        // ---- LN1: per-row partial sums (DPP over 16 lanes) -> LDS tree ----
        #pragma unroll
        for (int mt = 0; mt < 2; ++mt)
            #pragma unroll
            for (int reg = 0; reg < 4; ++reg) {
                float v  = acc1[mt][reg];
                float sv = red16(v);
                float sq = red16(v * v);
                if (c == 0) {
                    int r = mt * 16 + q * 4 + reg;
                    float2 p2; p2.x = sv; p2.y = sq;
                    *reinterpret_cast<float2*>(&red_part[mg][cw][r][0]) = p2;
                }
            }
        __syncthreads();                                   // (B) partials ready
        if (t < ET) {
            float s = 0.f, ss = 0.f;
            #pragma unroll
            for (int i = 0; i < 8; ++i) {
                float2 p2 = *reinterpret_cast<const float2*>(&red_part[t >> 5][i][t & 31][0]);
                s += p2.x; ss += p2.y;
            }
            float mu  = s * (1.f / 128.f);
            float var = ss * (1.f / 128.f) - mu * mu;
            float2 m2; m2.x = mu; m2.y = rsqrtf(var + LN_EPS);
            *reinterpret_cast<float2*>(&musig[0][t][0]) = m2;
        }
        __syncthreads();                                   // (C) mu/rs ready

        // ---- normalize -> h (bf16) into lds_a (overwrites ea; safe after C) ----
        #pragma unroll
        for (int mt = 0; mt < 2; ++mt)
            #pragma unroll
            for (int reg = 0; reg < 4; ++reg) {
                int r = mg * 32 + mt * 16 + q * 4 + reg;
                float2 m2 = *reinterpret_cast<const float2*>(&musig[0][r][0]);
                float h = (acc1[mt][reg] - m2.x) * m2.y * g1c + be1c;
                lds_a[r * PA + cw * 16 + c] = (short)f2bf(h);
            }
        __syncthreads();                                   // (D) h ready

        // ---- GEMM2: u = relu(h @ W1 + b1), this wave's 32 cols ----
        f4 acc2[2][2];
        acc2[0][0] = {0.f,0.f,0.f,0.f}; acc2[0][1] = {0.f,0.f,0.f,0.f};
        acc2[1][0] = {0.f,0.f,0.f,0.f}; acc2[1][1] = {0.f,0.f,0.f,0.f};
        #pragma unroll
        for (int k0 = 0; k0 < 4; ++k0)
            #pragma unroll
            for (int mt = 0; mt < 2; ++mt) {
                s8 a = *reinterpret_cast<const s8*>(&lds_a[(mg * 32 + mt * 16 + c) * PA + k0 * 32 + q * 8]);
                acc2[mt][0] = __builtin_amdgcn_mfma_f32_16x16x32_bf16(a, w1f[0][k0], acc2[mt][0], 0, 0, 0);
                acc2[mt][1] = __builtin_amdgcn_mfma_f32_16x16x32_bf16(a, w1f[1][k0], acc2[mt][1], 0, 0, 0);
            }
        #pragma unroll
        for (int mt = 0; mt < 2; ++mt)
            #pragma unroll
            for (int reg = 0; reg < 4; ++reg) {
                int r = mg * 32 + mt * 16 + q * 4 + reg;
                float u0 = fmaxf(acc2[mt][0][reg] + b1v0, 0.f);
                float u1 = fmaxf(acc2[mt][1][reg] + b1v1, 0.f);
                lds_u[r * PU + cw * 32 + c]      = (short)f2bf(u0);
                lds_u[r * PU + cw * 32 + 16 + c] = (short)f2bf(u1);
            }
        __syncthreads();                                   // (E) u ready

        // ---- GEMM3: y = h + u @ W2 + b2 (K=256), this wave's 16 cols ----
        f4 acc3[2];
        #pragma unroll
        for (int mt = 0; mt < 2; ++mt)
            #pragma unroll
            for (int reg = 0; reg < 4; ++reg) {
                int r = mg * 32 + mt * 16 + q * 4 + reg;
                acc3[mt][reg] = bf2f((unsigned short)lds_a[r * PA + cw * 16 + c]) + b2c;
            }
        #pragma unroll
        for (int k0 = 0; k0 < 8; ++k0)
            #pragma unroll
            for (int mt = 0; mt < 2; ++mt) {
                s8 a = *reinterpret_cast<const s8*>(&lds_u[(mg * 32 + mt * 16 + c) * PU + k0 * 32 + q * 8]);
                acc3[mt] = __builtin_amdgcn_mfma_f32_16x16x32_bf16(a, w2f[k0], acc3[mt], 0, 0, 0);
            }

        // ---- LN2 partials ----
        #pragma unroll
        for (int mt = 0; mt < 2; ++mt)
            #pragma unroll
            for (int reg = 0; reg < 4; ++reg) {
                float v  = acc3[mt][reg];
                float sv = red16(v);
                float sq = red16(v * v);
                if (c == 0) {
                    int r = mt * 16 + q * 4 + reg;
                    float2 p2; p2.x = sv; p2.y = sq;
                    *reinterpret_cast<float2*>(&red_part[mg][cw][r][0]) = p2;
                }
            }
        __syncthreads();                                   // (F) partials ready
        if (t < ET) {
            float s = 0.f, ss = 0.f;
            #pragma unroll
            for (int i = 0; i < 8; ++i) {
                float2 p2 = *reinterpret_cast<const float2*>(&red_part[t >> 5][i][t & 31][0]);
                s += p2.x; ss += p2.y;
            }
            float mu  = s * (1.f / 128.f);
            float var = ss * (1.f / 128.f) - mu * mu;
            float2 m2; m2.x = mu; m2.y = rsqrtf(var + LN_EPS);
            *reinterpret_cast<float2*>(&musig[1][t][0]) = m2;
        }
        __syncthreads();                                   // (G) mu/rs ready

        // ---- epilogue store ----
        #pragma unroll
        for (int mt = 0; mt < 2; ++mt)
            #pragma unroll
            for (int reg = 0; reg < 4; ++reg) {
                int r = mg * 32 + mt * 16 + q * 4 + reg;
                float2 m2 = *reinterpret_cast<const float2*>(&musig[1][r][0]);
                float o = (acc3[mt][reg] - m2.x) * m2.y * g2c + be2c;
                out[(size_t)(e0 + r) * 128 + cw * 16 + c] = o;
            }
    }
}

// ------------------------------------------------------------------ launch ---
extern "C" void kernel_launch(void* const* d_in, const int* in_sizes, int n_in,
                              void* d_out, int out_size, void* d_ws, size_t ws_size,
                              hipStream_t stream) {
    const float* x         = (const float*)d_in[0];
    const int*   ei        = (const int*)  d_in[1];
    const float* edge_attr = (const float*)d_in[2];
    const float* mask      = (const float*)d_in[3];
    const float* W_edge    = (const float*)d_in[5];
    const float* b_edge    = (const float*)d_in[6];
    const float* W1        = (const float*)d_in[7];
    const float* b1        = (const float*)d_in[8];
    const float* W2        = (const float*)d_in[9];
    const float* b2        = (const float*)d_in[10];
    const float* g1        = (const float*)d_in[11];
    const float* be1       = (const float*)d_in[12];
    const float* g2        = (const float*)d_in[13];
    const float* be2       = (const float*)d_in[14];

    float* node_out  = (float*)d_out;                       // [NN, DR]
    float* out_edges = (float*)d_out + (size_t)NN * DR;     // [NE, 128]

    char* ws = (char*)d_ws;
    float*          den = (float*)(ws);                          // 200 KB
    unsigned short* WcT = (unsigned short*)(ws + (256 << 10));   // 32 KB
    unsigned short* W1T = (unsigned short*)(ws + (256 << 10) + 32768);   // 64 KB
    unsigned short* W2T = (unsigned short*)(ws + (256 << 10) + 98304);   // 64 KB
    float*          P   = (float*)(ws + (1 << 20));              // 25.6 MB
    float*          Q   = (float*)(ws + (1 << 20) + 26214400);   // 25.6 MB

    hipMemsetAsync(node_out, 0, (size_t)NN * DR * sizeof(float), stream);
    hipMemsetAsync(den,      0, (size_t)NN * sizeof(float),      stream);

    scatter_kernel<<<(NE * 32) / 256, 256, 0, stream>>>(edge_attr, mask, ei, node_out, den);
    finalize_node_kernel<<<(NN * DR + 255) / 256, 256, 0, stream>>>(x, den, node_out);
    prep_w_kernel<<<320, 256, 0, stream>>>(W_edge, W1, W2, WcT, W1T, W2T);
    pq_kernel<<<(NN + 31) / 32, 256, 0, stream>>>(node_out, W_edge, b_edge, P, Q);
    ffn_kernel<<<256, 1024, 0, stream>>>(edge_attr, ei, P, Q, WcT, W1T, W2T,
                                         b1, b2, g1, be1, g2, be2, out_edges);
}

// Round 2
// 866.672 us; speedup vs baseline: 1.4608x; 1.2276x over previous
//
#include <hip/hip_runtime.h>

// PathCon FFN — round 3: replace float-atomic scatter with bin+gather CSR.
// deg (int atomics) -> scan (1 block) -> binfill (int atomics) -> gather
// (1 wave/node, coalesced 512B row reads, fused divide + x-tail write).
// finalize_node_kernel and node_out/den memsets deleted.

constexpr int NN = 50000;
constexpr int NE = 400000;
constexpr int DI = 128;
constexpr int DN = 6;
constexpr int DR = 134;
constexpr float LN_EPS = 1e-5f;

using f4 = __attribute__((ext_vector_type(4))) float;
using s8 = __attribute__((ext_vector_type(8))) short;

__device__ __forceinline__ unsigned short f2bf(float f) {
    unsigned u = __float_as_uint(f);
    u += 0x7fff + ((u >> 16) & 1);   // RNE
    return (unsigned short)(u >> 16);
}

__device__ __forceinline__ float bf2f(unsigned short b) {
    return __uint_as_float((unsigned)b << 16);
}

// Sum across each aligned 16-lane group via DPP row rotations (VALU pipe, no LDS).
__device__ __forceinline__ float red16(float v) {
    int x;
    x = __builtin_amdgcn_update_dpp(0, __float_as_int(v), 0x121, 0xf, 0xf, true); // row_ror:1
    v += __int_as_float(x);
    x = __builtin_amdgcn_update_dpp(0, __float_as_int(v), 0x122, 0xf, 0xf, true); // row_ror:2
    v += __int_as_float(x);
    x = __builtin_amdgcn_update_dpp(0, __float_as_int(v), 0x124, 0xf, 0xf, true); // row_ror:4
    v += __int_as_float(x);
    x = __builtin_amdgcn_update_dpp(0, __float_as_int(v), 0x128, 0xf, 0xf, true); // row_ror:8
    v += __int_as_float(x);
    return v;
}

// ------------------------------------------------------------ CSR build ---
__global__ __launch_bounds__(256) void deg_kernel(
    const float* __restrict__ mask, const int* __restrict__ ei,
    int* __restrict__ deg)
{
    int e = blockIdx.x * 256 + threadIdx.x;
    if (e >= NE) return;
    if (mask[e] != 0.f) atomicAdd(&deg[ei[NE + e]], 1);
}

__global__ __launch_bounds__(1024) void scan_kernel(
    const int* __restrict__ deg, int* __restrict__ offs, int* __restrict__ cursor)
{
    __shared__ int part[1024];
    const int t = threadIdx.x;
    constexpr int CH = (NN + 1023) / 1024;   // 49
    const int base = t * CH;
    const int lim  = min(base + CH, NN);

    int s = 0;
    for (int i = base; i < lim; ++i) s += deg[i];
    part[t] = s;
    __syncthreads();
    // Hillis-Steele inclusive scan over 1024 partials
    for (int off = 1; off < 1024; off <<= 1) {
        int add = (t >= off) ? part[t - off] : 0;
        __syncthreads();
        part[t] += add;
        __syncthreads();
    }
    int run = (t == 0) ? 0 : part[t - 1];
    for (int i = base; i < lim; ++i) {
        offs[i]   = run;
        cursor[i] = run;
        run += deg[i];
    }
    if (t == 1023) offs[NN] = part[1023];
}

__global__ __launch_bounds__(256) void binfill_kernel(
    const float* __restrict__ mask, const int* __restrict__ ei,
    int* __restrict__ cursor, int* __restrict__ bucket)
{
    int e = blockIdx.x * 256 + threadIdx.x;
    if (e >= NE) return;
    if (mask[e] != 0.f) {
        int pos = atomicAdd(&cursor[ei[NE + e]], 1);
        bucket[pos] = e;
    }
}

// one wave per node: sum masked edge_attr rows, divide, write node_rep row
__global__ __launch_bounds__(256) void gather_kernel(
    const float* __restrict__ edge_attr, const float* __restrict__ mask,
    const float* __restrict__ x, const int* __restrict__ offs,
    const int* __restrict__ bucket, float* __restrict__ node_out)
{
    int n = blockIdx.x * 4 + (threadIdx.x >> 6);
    if (n >= NN) return;
    const int lane = threadIdx.x & 63;
    const int beg = offs[n], end = offs[n + 1];
    float2 acc = make_float2(0.f, 0.f);
    float den = 0.f;
    for (int j = beg; j < end; ++j) {
        int e = bucket[j];
        float m = mask[e];
        float2 v = *reinterpret_cast<const float2*>(edge_attr + (size_t)e * 128 + lane * 2);
        acc.x += v.x * m;
        acc.y += v.y * m;
        den   += m;
    }
    float inv = 1.f / (den + 1.f);
    float2 o = make_float2(acc.x * inv, acc.y * inv);
    *reinterpret_cast<float2*>(node_out + (size_t)n * DR + lane * 2) = o;
    if (lane < DN) node_out[(size_t)n * DR + DI + lane] = x[n * DN + lane];
}

// ----------------------------------------------------- bf16 weight prep ---
// WcT'[n][k] = W_edge[268+k][n] + (k==n)   (128x128)
// W1T [n][k] = W1[k][n]                    (256x128)
// W2T [n][k] = W2[k][n]                    (128x256)
__global__ __launch_bounds__(256) void prep_w_kernel(
    const float* __restrict__ W_edge, const float* __restrict__ W1,
    const float* __restrict__ W2,
    unsigned short* __restrict__ WcT, unsigned short* __restrict__ W1T,
    unsigned short* __restrict__ W2T)
{
    int idx = blockIdx.x * 256 + threadIdx.x;
    if (idx < 16384) {
        int n = idx >> 7, k = idx & 127;
        float v = W_edge[(268 + k) * 128 + n] + (k == n ? 1.f : 0.f);
        WcT[n * 128 + k] = f2bf(v);
    } else if (idx < 49152) {
        int j = idx - 16384;
        int n = j >> 7, k = j & 127;
        W1T[n * 128 + k] = f2bf(W1[k * 256 + n]);
    } else if (idx < 81920) {
        int j = idx - 49152;
        int n = j >> 8, k = j & 255;
        W2T[n * 256 + k] = f2bf(W2[k * 128 + n]);
    }
}

// ------------------------------------------------ P/Q node-level GEMMs ---
// P = node_rep @ Wa + b_edge ; Q = node_rep @ Wb   (K=134 padded to 136)
__global__ __launch_bounds__(256) void pq_kernel(
    const float* __restrict__ nr, const float* __restrict__ W_edge,
    const float* __restrict__ b_edge,
    float* __restrict__ P, float* __restrict__ Q)
{
    __shared__ float As[32 * 136];
    const int t = threadIdx.x;
    const int n0 = blockIdx.x * 32;

    for (int idx = t; idx < 32 * 136; idx += 256) {
        int n = idx / 136, k = idx - n * 136;
        float v = 0.f;
        if (n0 + n < NN && k < DR) v = nr[(size_t)(n0 + n) * DR + k];
        As[idx] = v;
    }
    __syncthreads();

    const int et = t >> 5, jt = t & 31;
    float4 accP[4], accQ[4];
    #pragma unroll
    for (int i = 0; i < 4; ++i) {
        accP[i] = make_float4(0.f, 0.f, 0.f, 0.f);
        accQ[i] = make_float4(0.f, 0.f, 0.f, 0.f);
    }
    for (int k0 = 0; k0 < 136; k0 += 4) {
        float4 wa[4], wb[4];
        #pragma unroll
        for (int d = 0; d < 4; ++d) {
            wa[d] = *reinterpret_cast<const float4*>(&W_edge[(size_t)(k0 + d) * 128 + 4 * jt]);
            wb[d] = *reinterpret_cast<const float4*>(&W_edge[(size_t)(134 + k0 + d) * 128 + 4 * jt]);
        }
        #pragma unroll
        for (int i = 0; i < 4; ++i) {
            float4 a4 = *reinterpret_cast<const float4*>(&As[(4 * et + i) * 136 + k0]);
            accP[i].x += a4.x * wa[0].x + a4.y * wa[1].x + a4.z * wa[2].x + a4.w * wa[3].x;
            accP[i].y += a4.x * wa[0].y + a4.y * wa[1].y + a4.z * wa[2].y + a4.w * wa[3].y;
            accP[i].z += a4.x * wa[0].z + a4.y * wa[1].z + a4.z * wa[2].z + a4.w * wa[3].z;
            accP[i].w += a4.x * wa[0].w + a4.y * wa[1].w + a4.z * wa[2].w + a4.w * wa[3].w;
            accQ[i].x += a4.x * wb[0].x + a4.y * wb[1].x + a4.z * wb[2].x + a4.w * wb[3].x;
            accQ[i].y += a4.x * wb[0].y + a4.y * wb[1].y + a4.z * wb[2].y + a4.w * wb[3].y;
            accQ[i].z += a4.x * wb[0].z + a4.y * wb[1].z + a4.z * wb[2].z + a4.w * wb[3].z;
            accQ[i].w += a4.x * wb[0].w + a4.y * wb[1].w + a4.z * wb[2].w + a4.w * wb[3].w;
        }
    }
    float4 bev = *reinterpret_cast<const float4*>(&b_edge[4 * jt]);
    #pragma unroll
    for (int i = 0; i < 4; ++i) {
        int n = n0 + 4 * et + i;
        if (n < NN) {
            float4 p = accP[i];
            p.x += bev.x; p.y += bev.y; p.z += bev.z; p.w += bev.w;
            *reinterpret_cast<float4*>(&P[(size_t)n * 128 + 4 * jt]) = p;
            *reinterpret_cast<float4*>(&Q[(size_t)n * 128 + 4 * jt]) = accQ[i];
        }
    }
}

// -------------------------------------------------------------- fused FFN ---
// Block: 1024 threads = 16 waves = 2 m-groups (32 edges each) x 8 col-waves.
// Weights held in VGPRs for the whole kernel (loaded once per block).
constexpr int PA = 136;          // pitch (shorts) of ea/h tile rows
constexpr int PU = 264;          // pitch (shorts) of u tile rows
constexpr int ET = 64;           // edges per block-iteration
constexpr int NTILE = NE / ET;   // 6250

__global__ __launch_bounds__(1024, 4) void ffn_kernel(
    const float* __restrict__ edge_attr,  // [NE, 128]
    const int* __restrict__ ei,           // [2, NE]
    const float* __restrict__ P,          // [NN, 128]
    const float* __restrict__ Q,          // [NN, 128]
    const unsigned short* __restrict__ WcT,   // [128][128] bf16 (Wc+I)^T
    const unsigned short* __restrict__ W1T,   // [256][128] bf16
    const unsigned short* __restrict__ W2T,   // [128][256] bf16
    const float* __restrict__ b1, const float* __restrict__ b2,
    const float* __restrict__ g1, const float* __restrict__ be1,
    const float* __restrict__ g2, const float* __restrict__ be2,
    float* __restrict__ out)              // [NE, 128]
{
    __shared__ short lds_a[ET * PA];          // ea tile, later h tile (17408 B)
    __shared__ short lds_u[ET * PU];          // u tile (33792 B)
    __shared__ float red_part[2][8][32][2];   // [mg][cw][row][s,ss] (4096 B)
    __shared__ float musig[2][ET][2];         // [ln][row][mu,rs]    (1024 B)

    const int t    = threadIdx.x;
    const int w    = t >> 6;
    const int lane = t & 63;
    const int q    = lane >> 4;     // 0..3
    const int c    = lane & 15;     // 0..15
    const int mg   = w >> 3;        // 0..1   (m-group: which 32 edges)
    const int cw   = w & 7;         // 0..7   (col-slice)

    // ---- persistent weight fragments (loaded once per block) ----
    s8 wcf[4], w1f[2][4], w2f[8];                 // 80 VGPRs
    #pragma unroll
    for (int k0 = 0; k0 < 4; ++k0)
        wcf[k0] = *reinterpret_cast<const s8*>(WcT + (cw * 16 + c) * 128 + k0 * 32 + q * 8);
    #pragma unroll
    for (int nt = 0; nt < 2; ++nt)
        #pragma unroll
        for (int k0 = 0; k0 < 4; ++k0)
            w1f[nt][k0] = *reinterpret_cast<const s8*>(W1T + (cw * 32 + nt * 16 + c) * 128 + k0 * 32 + q * 8);
    #pragma unroll
    for (int k0 = 0; k0 < 8; ++k0)
        w2f[k0] = *reinterpret_cast<const s8*>(W2T + (cw * 16 + c) * 256 + k0 * 32 + q * 8);

    const float g1c  = g1[cw * 16 + c],  be1c = be1[cw * 16 + c];
    const float b1v0 = b1[cw * 32 + c],  b1v1 = b1[cw * 32 + 16 + c];
    const float b2c  = b2[cw * 16 + c];
    const float g2c  = g2[cw * 16 + c],  be2c = be2[cw * 16 + c];

    const int srow = t >> 4;    // staging: 0..63
    const int sti  = t & 15;    // staging: 16 threads per row

    for (int tile = blockIdx.x; tile < NTILE; tile += gridDim.x) {
        const int e0 = tile * ET;

        // ---- stage ea tile -> bf16 LDS (all 1024 threads, 8 floats each) ----
        {
            const float4* src = reinterpret_cast<const float4*>(
                edge_attr + (size_t)(e0 + srow) * 128 + sti * 8);
            float4 v0 = src[0], v1 = src[1];
            s8 bb;
            bb[0] = (short)f2bf(v0.x); bb[1] = (short)f2bf(v0.y);
            bb[2] = (short)f2bf(v0.z); bb[3] = (short)f2bf(v0.w);
            bb[4] = (short)f2bf(v1.x); bb[5] = (short)f2bf(v1.y);
            bb[6] = (short)f2bf(v1.z); bb[7] = (short)f2bf(v1.w);
            *reinterpret_cast<s8*>(&lds_a[srow * PA + sti * 8]) = bb;
        }
        __syncthreads();                                   // (A) ea ready

        // ---- GEMM1: ea @ (Wc+I), this wave's 16 cols x 32 edges ----
        f4 acc1[2];
        acc1[0] = {0.f, 0.f, 0.f, 0.f};
        acc1[1] = {0.f, 0.f, 0.f, 0.f};
        #pragma unroll
        for (int k0 = 0; k0 < 4; ++k0)
            #pragma unroll
            for (int mt = 0; mt < 2; ++mt) {
                s8 a = *reinterpret_cast<const s8*>(&lds_a[(mg * 32 + mt * 16 + c) * PA + k0 * 32 + q * 8]);
                acc1[mt] = __builtin_amdgcn_mfma_f32_16x16x32_bf16(a, wcf[k0], acc1[mt], 0, 0, 0);
            }

        // ---- residual: + P[row_e] + Q[col_e] (only this wave's 16 cols) ----
        #pragma unroll
        for (int mt = 0; mt < 2; ++mt)
            #pragma unroll
            for (int reg = 0; reg < 4; ++reg) {
                int e  = e0 + mg * 32 + mt * 16 + q * 4 + reg;
                int er = ei[e], ec = ei[NE + e];
                acc1[mt][reg] += P[(size_t)er * 128 + cw * 16 + c]
                               + Q[(size_t)ec * 128 + cw * 16 + c];
            }

        // ---- LN1: per-row partial sums (DPP over 16 lanes) -> LDS tree ----
        #pragma unroll
        for (int mt = 0; mt < 2; ++mt)
            #pragma unroll
            for (int reg = 0; reg < 4; ++reg) {
                float v  = acc1[mt][reg];
                float sv = red16(v);
                float sq = red16(v * v);
                if (c == 0) {
                    int r = mt * 16 + q * 4 + reg;
                    float2 p2; p2.x = sv; p2.y = sq;
                    *reinterpret_cast<float2*>(&red_part[mg][cw][r][0]) = p2;
                }
            }
        __syncthreads();                                   // (B) partials ready
        if (t < ET) {
            float s = 0.f, ss = 0.f;
            #pragma unroll
            for (int i = 0; i < 8; ++i) {
                float2 p2 = *reinterpret_cast<const float2*>(&red_part[t >> 5][i][t & 31][0]);
                s += p2.x; ss += p2.y;
            }
            float mu  = s * (1.f / 128.f);
            float var = ss * (1.f / 128.f) - mu * mu;
            float2 m2; m2.x = mu; m2.y = rsqrtf(var + LN_EPS);
            *reinterpret_cast<float2*>(&musig[0][t][0]) = m2;
        }
        __syncthreads();                                   // (C) mu/rs ready

        // ---- normalize -> h (bf16) into lds_a (overwrites ea; safe after C) ----
        #pragma unroll
        for (int mt = 0; mt < 2; ++mt)
            #pragma unroll
            for (int reg = 0; reg < 4; ++reg) {
                int r = mg * 32 + mt * 16 + q * 4 + reg;
                float2 m2 = *reinterpret_cast<const float2*>(&musig[0][r][0]);
                float h = (acc1[mt][reg] - m2.x) * m2.y * g1c + be1c;
                lds_a[r * PA + cw * 16 + c] = (short)f2bf(h);
            }
        __syncthreads();                                   // (D) h ready

        // ---- GEMM2: u = relu(h @ W1 + b1), this wave's 32 cols ----
        f4 acc2[2][2];
        acc2[0][0] = {0.f,0.f,0.f,0.f}; acc2[0][1] = {0.f,0.f,0.f,0.f};
        acc2[1][0] = {0.f,0.f,0.f,0.f}; acc2[1][1] = {0.f,0.f,0.f,0.f};
        #pragma unroll
        for (int k0 = 0; k0 < 4; ++k0)
            #pragma unroll
            for (int mt = 0; mt < 2; ++mt) {
                s8 a = *reinterpret_cast<const s8*>(&lds_a[(mg * 32 + mt * 16 + c) * PA + k0 * 32 + q * 8]);
                acc2[mt][0] = __builtin_amdgcn_mfma_f32_16x16x32_bf16(a, w1f[0][k0], acc2[mt][0], 0, 0, 0);
                acc2[mt][1] = __builtin_amdgcn_mfma_f32_16x16x32_bf16(a, w1f[1][k0], acc2[mt][1], 0, 0, 0);
            }
        #pragma unroll
        for (int mt = 0; mt < 2; ++mt)
            #pragma unroll
            for (int reg = 0; reg < 4; ++reg) {
                int r = mg * 32 + mt * 16 + q * 4 + reg;
                float u0 = fmaxf(acc2[mt][0][reg] + b1v0, 0.f);
                float u1 = fmaxf(acc2[mt][1][reg] + b1v1, 0.f);
                lds_u[r * PU + cw * 32 + c]      = (short)f2bf(u0);
                lds_u[r * PU + cw * 32 + 16 + c] = (short)f2bf(u1);
            }
        __syncthreads();                                   // (E) u ready

        // ---- GEMM3: y = h + u @ W2 + b2 (K=256), this wave's 16 cols ----
        f4 acc3[2];
        #pragma unroll
        for (int mt = 0; mt < 2; ++mt)
            #pragma unroll
            for (int reg = 0; reg < 4; ++reg) {
                int r = mg * 32 + mt * 16 + q * 4 + reg;
                acc3[mt][reg] = bf2f((unsigned short)lds_a[r * PA + cw * 16 + c]) + b2c;
            }
        #pragma unroll
        for (int k0 = 0; k0 < 8; ++k0)
            #pragma unroll
            for (int mt = 0; mt < 2; ++mt) {
                s8 a = *reinterpret_cast<const s8*>(&lds_u[(mg * 32 + mt * 16 + c) * PU + k0 * 32 + q * 8]);
                acc3[mt] = __builtin_amdgcn_mfma_f32_16x16x32_bf16(a, w2f[k0], acc3[mt], 0, 0, 0);
            }

        // ---- LN2 partials ----
        #pragma unroll
        for (int mt = 0; mt < 2; ++mt)
            #pragma unroll
            for (int reg = 0; reg < 4; ++reg) {
                float v  = acc3[mt][reg];
                float sv = red16(v);
                float sq = red16(v * v);
                if (c == 0) {
                    int r = mt * 16 + q * 4 + reg;
                    float2 p2; p2.x = sv; p2.y = sq;
                    *reinterpret_cast<float2*>(&red_part[mg][cw][r][0]) = p2;
                }
            }
        __syncthreads();                                   // (F) partials ready
        if (t < ET) {
            float s = 0.f, ss = 0.f;
            #pragma unroll
            for (int i = 0; i < 8; ++i) {
                float2 p2 = *reinterpret_cast<const float2*>(&red_part[t >> 5][i][t & 31][0]);
                s += p2.x; ss += p2.y;
            }
            float mu  = s * (1.f / 128.f);
            float var = ss * (1.f / 128.f) - mu * mu;
            float2 m2; m2.x = mu; m2.y = rsqrtf(var + LN_EPS);
            *reinterpret_cast<float2*>(&musig[1][t][0]) = m2;
        }
        __syncthreads();                                   // (G) mu/rs ready

        // ---- epilogue store ----
        #pragma unroll
        for (int mt = 0; mt < 2; ++mt)
            #pragma unroll
            for (int reg = 0; reg < 4; ++reg) {
                int r = mg * 32 + mt * 16 + q * 4 + reg;
                float2 m2 = *reinterpret_cast<const float2*>(&musig[1][r][0]);
                float o = (acc3[mt][reg] - m2.x) * m2.y * g2c + be2c;
                out[(size_t)(e0 + r) * 128 + cw * 16 + c] = o;
            }
    }
}

// ------------------------------------------------------------------ launch ---
extern "C" void kernel_launch(void* const* d_in, const int* in_sizes, int n_in,
                              void* d_out, int out_size, void* d_ws, size_t ws_size,
                              hipStream_t stream) {
    const float* x         = (const float*)d_in[0];
    const int*   ei        = (const int*)  d_in[1];
    const float* edge_attr = (const float*)d_in[2];
    const float* mask      = (const float*)d_in[3];
    const float* W_edge    = (const float*)d_in[5];
    const float* b_edge    = (const float*)d_in[6];
    const float* W1        = (const float*)d_in[7];
    const float* b1        = (const float*)d_in[8];
    const float* W2        = (const float*)d_in[9];
    const float* b2        = (const float*)d_in[10];
    const float* g1        = (const float*)d_in[11];
    const float* be1       = (const float*)d_in[12];
    const float* g2        = (const float*)d_in[13];
    const float* be2       = (const float*)d_in[14];

    float* node_out  = (float*)d_out;                       // [NN, DR]
    float* out_edges = (float*)d_out + (size_t)NN * DR;     // [NE, 128]

    char* ws = (char*)d_ws;
    int*            deg    = (int*)(ws);                         // 256 KB region
    int*            offs   = (int*)(ws + (256 << 10));           // 256 KB (NN+1 ints)
    int*            cursor = (int*)(ws + (512 << 10));           // 256 KB
    unsigned short* WcT    = (unsigned short*)(ws + (768 << 10));          // 32 KB
    unsigned short* W1T    = (unsigned short*)(ws + (768 << 10) + 32768);  // 64 KB
    unsigned short* W2T    = (unsigned short*)(ws + (768 << 10) + 98304);  // 64 KB
    int*            bucket = (int*)(ws + (1 << 20));             // 1.6 MB, aliases P (dead until pq)
    float*          P      = (float*)(ws + (1 << 20));           // 25.6 MB
    float*          Q      = (float*)(ws + (1 << 20) + 26214400);// 25.6 MB

    hipMemsetAsync(deg, 0, (size_t)NN * sizeof(int), stream);

    deg_kernel<<<(NE + 255) / 256, 256, 0, stream>>>(mask, ei, deg);
    scan_kernel<<<1, 1024, 0, stream>>>(deg, offs, cursor);
    binfill_kernel<<<(NE + 255) / 256, 256, 0, stream>>>(mask, ei, cursor, bucket);
    gather_kernel<<<(NN + 3) / 4, 256, 0, stream>>>(edge_attr, mask, x, offs, bucket, node_out);
    prep_w_kernel<<<320, 256, 0, stream>>>(W_edge, W1, W2, WcT, W1T, W2T);
    pq_kernel<<<(NN + 31) / 32, 256, 0, stream>>>(node_out, W_edge, b_edge, P, Q);
    ffn_kernel<<<256, 1024, 0, stream>>>(edge_attr, ei, P, Q, WcT, W1T, W2T,
                                         b1, b2, g1, be1, g2, be2, out_edges);
}